// Round 16
// baseline (290.120 us; speedup 1.0000x reference)
//
#include <hip/hip_runtime.h>
#include <math.h>

#define C_   256
#define CQ_  32
#define H_   128
#define W_   128
#define HW_  (H_ * W_)
#define OC_  320   // 0..31 q, 32..63 k, 64..319 v

typedef __attribute__((ext_vector_type(8))) short  s8v;   // 8 bf16 (A/B frag)
typedef __attribute__((ext_vector_type(4))) float  f4v;   // 4 fp32 (C/D frag)
typedef __attribute__((ext_vector_type(8))) unsigned short u8v;
typedef __attribute__((ext_vector_type(4))) unsigned short u4v;

__device__ inline unsigned short f2bf(float f) {
    unsigned int u = __float_as_uint(f);
    unsigned int r = (u + 0x7fffu + ((u >> 16) & 1u)) >> 16;
    return (unsigned short)r;
}
__device__ inline float bfu(unsigned short u) {
    return __uint_as_float((unsigned int)u << 16);
}

// ------------------------------------------------ K0: W -> bf16 (320x256)
__global__ __launch_bounds__(256) void k_wconv(
    const float* __restrict__ wq, const float* __restrict__ wk,
    const float* __restrict__ wv, unsigned short* __restrict__ Wb)
{
    int idx4 = blockIdx.x * 256 + threadIdx.x;     // 20480 total
    int e = idx4 * 4;
    int oc = e >> 8, k = e & 255;
    const float* src;
    if (oc < 32)      src = wq + (size_t)oc * C_ + k;
    else if (oc < 64) src = wk + (size_t)(oc - 32) * C_ + k;
    else              src = wv + (size_t)(oc - 64) * C_ + k;
    float4 v = *(const float4*)src;
    u4v o;
    o[0] = f2bf(v.x); o[1] = f2bf(v.y); o[2] = f2bf(v.z); o[3] = f2bf(v.w);
    *(u4v*)(Wb + e) = o;
}

// ---------------------------------------------------------- K1: QKV MFMA GEMM
// R10 v5 (proven 90 µs) + T5 setprio around MFMA cluster.
__global__ __launch_bounds__(256) void k_qkv(
    const float* __restrict__ x, const unsigned short* __restrict__ Wb,
    const float* __restrict__ bq, const float* __restrict__ bk,
    const float* __restrict__ bv,
    unsigned short* __restrict__ qkv, int b0)
{
    __shared__ __align__(16) unsigned short Wl[2][64][72];   // 18.4 KB
    __shared__ __align__(16) unsigned int   Xp[2][32 * 132]; // 33.8 KB
    const int t = threadIdx.x;
    const int lane = t & 63;
    const int wave = t >> 6;
    const int n0 = blockIdx.x * 128;
    const int ocblk = blockIdx.y * 64;
    const int bb = blockIdx.z;
    const float* xb = x + (size_t)(b0 + bb) * C_ * HW_;

    const int lg = lane >> 4;      // 0..3
    const int ll = lane & 15;      // 0..15
    const int n_w = wave * 32;

    const int kp8 = t >> 5;          // 0..7
    const int n4  = (t & 31) * 4;    // 0..124
    const int wrow = t >> 3;         // 0..31
    const int wcg  = (t & 7) * 8;    // 0..56 (shorts)
    float4 ra[4], rb[4];
    u8v wreg[2];

    // ---- prologue: chunk 0 -> regs -> buf0; issue chunk 1 loads
    #pragma unroll
    for (int p = 0; p < 4; ++p) {
        int krow = (p * 8 + kp8) * 2;
        ra[p] = *(const float4*)(xb + (size_t)krow * HW_ + n0 + n4);
        rb[p] = *(const float4*)(xb + (size_t)(krow + 1) * HW_ + n0 + n4);
    }
    #pragma unroll
    for (int q = 0; q < 2; ++q)
        wreg[q] = *(const u8v*)(Wb + (size_t)(ocblk + wrow + q * 32) * C_ + wcg);

    #pragma unroll
    for (int p = 0; p < 4; ++p) {
        uint4 d;
        const float* af  = (const float*)&ra[p];
        const float* bf_ = (const float*)&rb[p];
        #pragma unroll
        for (int i = 0; i < 4; ++i) {
            unsigned int lo = (__float_as_uint(af[i])  + 0x8000u) >> 16;
            unsigned int hi = (__float_as_uint(bf_[i]) + 0x8000u) & 0xffff0000u;
            ((unsigned int*)&d)[i] = hi | lo;
        }
        *(uint4*)&Xp[0][(p * 8 + kp8) * 132 + n4] = d;
    }
    #pragma unroll
    for (int q = 0; q < 2; ++q)
        *(u8v*)&Wl[0][wrow + q * 32][wcg] = wreg[q];

    #pragma unroll
    for (int p = 0; p < 4; ++p) {
        int krow = 64 + (p * 8 + kp8) * 2;
        ra[p] = *(const float4*)(xb + (size_t)krow * HW_ + n0 + n4);
        rb[p] = *(const float4*)(xb + (size_t)(krow + 1) * HW_ + n0 + n4);
    }
    #pragma unroll
    for (int q = 0; q < 2; ++q)
        wreg[q] = *(const u8v*)(Wb + (size_t)(ocblk + wrow + q * 32) * C_ + 64 + wcg);

    f4v acc[4][2];
    #pragma unroll
    for (int mr = 0; mr < 4; ++mr)
        #pragma unroll
        for (int nr = 0; nr < 2; ++nr)
            acc[mr][nr] = (f4v){0.f, 0.f, 0.f, 0.f};

    __syncthreads();   // buf0 ready

    #pragma unroll
    for (int kc = 0; kc < 4; ++kc) {
        const int cur = kc & 1;
        if (kc < 3) {
            #pragma unroll
            for (int p = 0; p < 4; ++p) {
                uint4 d;
                const float* af  = (const float*)&ra[p];
                const float* bf_ = (const float*)&rb[p];
                #pragma unroll
                for (int i = 0; i < 4; ++i) {
                    unsigned int lo = (__float_as_uint(af[i])  + 0x8000u) >> 16;
                    unsigned int hi = (__float_as_uint(bf_[i]) + 0x8000u) & 0xffff0000u;
                    ((unsigned int*)&d)[i] = hi | lo;
                }
                *(uint4*)&Xp[cur ^ 1][(p * 8 + kp8) * 132 + n4] = d;
            }
            #pragma unroll
            for (int q = 0; q < 2; ++q)
                *(u8v*)&Wl[cur ^ 1][wrow + q * 32][wcg] = wreg[q];
        }
        if (kc < 2) {
            #pragma unroll
            for (int p = 0; p < 4; ++p) {
                int krow = (kc + 2) * 64 + (p * 8 + kp8) * 2;
                ra[p] = *(const float4*)(xb + (size_t)krow * HW_ + n0 + n4);
                rb[p] = *(const float4*)(xb + (size_t)(krow + 1) * HW_ + n0 + n4);
            }
            #pragma unroll
            for (int q = 0; q < 2; ++q)
                wreg[q] = *(const u8v*)(
                    Wb + (size_t)(ocblk + wrow + q * 32) * C_ + (kc + 2) * 64 + wcg);
        }
        __builtin_amdgcn_s_setprio(1);
        #pragma unroll
        for (int ks = 0; ks < 2; ++ks) {
            s8v afr[4];
            #pragma unroll
            for (int mr = 0; mr < 4; ++mr)
                afr[mr] = *(const s8v*)&Wl[cur][mr * 16 + ll][ks * 32 + lg * 8];
            #pragma unroll
            for (int nr = 0; nr < 2; ++nr) {
                int4 bd;
                #pragma unroll
                for (int e2 = 0; e2 < 4; ++e2)
                    ((int*)&bd)[e2] =
                        Xp[cur][(ks * 16 + lg * 4 + e2) * 132 + n_w + nr * 16 + ll];
                s8v bfr = *(s8v*)&bd;
                #pragma unroll
                for (int mr = 0; mr < 4; ++mr)
                    acc[mr][nr] = __builtin_amdgcn_mfma_f32_16x16x32_bf16(
                        afr[mr], bfr, acc[mr][nr], 0, 0, 0);
            }
        }
        __builtin_amdgcn_s_setprio(0);
        __syncthreads();   // buf[cur^1] writes visible; buf[cur] reads done
    }

    #pragma unroll
    for (int mr = 0; mr < 4; ++mr) {
        float bias[4];
        #pragma unroll
        for (int r = 0; r < 4; ++r) {
            int oc = ocblk + mr * 16 + lg * 4 + r;
            if (oc < 32)      bias[r] = bq[oc];
            else if (oc < 64) bias[r] = bk[oc - 32];
            else              bias[r] = bv[oc - 64];
        }
        #pragma unroll
        for (int nr = 0; nr < 2; ++nr) {
            int n = n0 + n_w + nr * 16 + ll;
            #pragma unroll
            for (int r = 0; r < 4; ++r) {
                int oc = ocblk + mr * 16 + lg * 4 + r;
                qkv[((size_t)bb * OC_ + oc) * HW_ + n] = f2bf(acc[mr][nr][r] + bias[r]);
            }
        }
    }
}

// ------------------------------------------------- K1b: transpose to (b,w,oc,h)
__global__ __launch_bounds__(256) void k_transpose_qkv(
    const unsigned short* __restrict__ qkv, unsigned short* __restrict__ qkv_t)
{
    __shared__ unsigned short tile[32][34];
    const int bb = blockIdx.z;
    const int oc = blockIdx.y;
    const int th = (blockIdx.x & 3) * 32;
    const int tw = (blockIdx.x >> 2) * 32;
    const unsigned short* src = qkv + ((size_t)bb * OC_ + oc) * HW_;
    #pragma unroll
    for (int r = 0; r < 4; ++r) {
        int h = threadIdx.y * 4 + r;
        tile[h][threadIdx.x] = src[(size_t)(th + h) * W_ + tw + threadIdx.x];
    }
    __syncthreads();
    unsigned short* dst = qkv_t + (size_t)bb * W_ * OC_ * H_;
    #pragma unroll
    for (int r = 0; r < 4; ++r) {
        int wl = threadIdx.y * 4 + r;
        dst[((size_t)(tw + wl) * OC_ + oc) * H_ + th + threadIdx.x] = tile[threadIdx.x][wl];
    }
}

// ---------------------------------------------------------------- shared helpers
__device__ inline void stage_KQ(const unsigned short* base, int cstride,
                                unsigned int* Ktp, unsigned int* Qp, int t)
{
    {   // Ktp: 128 rows x 2 halves = 256 units
        int i = t & 127, half = t >> 7, c0 = half * 16;
        unsigned int kr[16];
        #pragma unroll
        for (int cc = 0; cc < 16; ++cc)
            kr[cc] = base[(size_t)(32 + c0 + cc) * cstride + i];
        uint4 d0, d1;
        #pragma unroll
        for (int e2 = 0; e2 < 4; ++e2)
            ((unsigned int*)&d0)[e2] = kr[2 * e2] | (kr[2 * e2 + 1] << 16);
        #pragma unroll
        for (int e2 = 0; e2 < 4; ++e2)
            ((unsigned int*)&d1)[e2] = kr[8 + 2 * e2] | (kr[9 + 2 * e2] << 16);
        *(uint4*)&Ktp[i * 20 + half * 8]     = d0;
        *(uint4*)&Ktp[i * 20 + half * 8 + 4] = d1;
    }
    {   // Qp: 16 c2 x 16 j-groups = 256 units
        int c2 = t >> 4, j8 = (t & 15) * 8;
        u8v qa = *(const u8v*)(base + (size_t)(2 * c2) * cstride + j8);
        u8v qb = *(const u8v*)(base + (size_t)(2 * c2 + 1) * cstride + j8);
        uint4 e0, e1;
        #pragma unroll
        for (int e = 0; e < 4; ++e)
            ((unsigned int*)&e0)[e] =
                (unsigned int)qa[e] | ((unsigned int)qb[e] << 16);
        #pragma unroll
        for (int e = 0; e < 4; ++e)
            ((unsigned int*)&e1)[e] =
                (unsigned int)qa[4 + e] | ((unsigned int)qb[4 + e] << 16);
        *(uint4*)&Qp[c2 * 132 + j8]     = e0;
        *(uint4*)&Qp[c2 * 132 + j8 + 4] = e1;
    }
}

__device__ inline f4v eqk_mfma(const unsigned int* Ktp, const unsigned int* Qp,
                               int mr, int j, int lg, int ll)
{
    s8v afr = *(const s8v*)&Ktp[(mr * 16 + ll) * 20 + lg * 4];
    int4 bd;
    #pragma unroll
    for (int e2 = 0; e2 < 4; ++e2)
        ((int*)&bd)[e2] = Qp[(lg * 4 + e2) * 132 + j];
    s8v bfr = *(s8v*)&bd;
    return __builtin_amdgcn_mfma_f32_16x16x32_bf16(
        afr, bfr, (f4v){0.f, 0.f, 0.f, 0.f}, 0, 0, 0);
}

// ----------------------- K2: stats, both axes (mode = blockIdx.y; 0=h, 1=w)
__global__ __launch_bounds__(256) void k_stats(
    const unsigned short* __restrict__ qkv_t, const unsigned short* __restrict__ qkv,
    float* __restrict__ mh, float* __restrict__ sh,
    float* __restrict__ mw, float* __restrict__ sw)
{
    __shared__ __align__(16) unsigned int Ktp[128 * 20];
    __shared__ __align__(16) unsigned int Qp[16 * 132];
    const int t = threadIdx.x;
    const int pos = blockIdx.x;          // beta (mode 0) or alpha (mode 1)
    const int mode = blockIdx.y;
    const int bb = blockIdx.z;
    const unsigned short* base;
    int cstride;
    if (mode == 0) {
        base = qkv_t + ((size_t)bb * W_ + pos) * OC_ * H_;
        cstride = H_;
    } else {
        base = qkv + (size_t)bb * OC_ * HW_ + (size_t)pos * W_;
        cstride = HW_;
    }
    stage_KQ(base, cstride, Ktp, Qp, t);
    __syncthreads();

    const int lane = t & 63;
    const int wv = t >> 6;
    const int lg = lane >> 4;
    const int ll = lane & 15;

    #pragma unroll
    for (int ml = 0; ml < 2; ++ml) {
        const int mr = wv * 2 + ml;
        const int i0 = mr * 16 + lg * 4;
        f4v ef[8];
        #pragma unroll
        for (int nt = 0; nt < 8; ++nt) {
            f4v e = eqk_mfma(Ktp, Qp, mr, nt * 16 + ll, lg, ll);
            if (mode == 0) {
                int j = nt * 16 + ll;
                #pragma unroll
                for (int r = 0; r < 4; ++r)
                    if (i0 + r == j) e[r] = -INFINITY;   // diag mask (e_h only)
            }
            ef[nt] = e;
        }
        #pragma unroll
        for (int r = 0; r < 4; ++r) {
            float mm = -INFINITY;
            #pragma unroll
            for (int nt = 0; nt < 8; ++nt) mm = fmaxf(mm, ef[nt][r]);
            #pragma unroll
            for (int s = 1; s < 16; s <<= 1) mm = fmaxf(mm, __shfl_xor(mm, s));
            float ss = 0.f;
            #pragma unroll
            for (int nt = 0; nt < 8; ++nt) ss += __expf(ef[nt][r] - mm);
            #pragma unroll
            for (int s = 1; s < 16; s <<= 1) ss += __shfl_xor(ss, s);
            if (ll == 0) {
                int i = i0 + r;
                if (mode == 0) {
                    mh[((size_t)bb * H_ + i) * W_ + pos] = mm;
                    sh[((size_t)bb * H_ + i) * W_ + pos] = ss;
                } else {
                    mw[((size_t)bb * H_ + pos) * W_ + i] = mm;
                    sw[((size_t)bb * H_ + pos) * W_ + i] = ss;
                }
            }
        }
    }
}

// ------------------------------- K2c: combine stats -> m_comb, d_inv (+transposed)
__global__ __launch_bounds__(256) void k_prep(
    const float* __restrict__ mh, const float* __restrict__ sh,
    const float* __restrict__ mw, const float* __restrict__ sw,
    float* __restrict__ mc, float* __restrict__ dv,
    float* __restrict__ mct, float* __restrict__ dvt, int n)
{
    int idx = blockIdx.x * 256 + threadIdx.x;
    if (idx >= n) return;
    float m1 = mh[idx], s1 = sh[idx], m2 = mw[idx], s2 = sw[idx];
    float m = fmaxf(m1, m2);
    float d = 1.f / (s1 * __expf(m1 - m) + s2 * __expf(m2 - m));
    mc[idx] = m; dv[idx] = d;
    int q = idx & (W_ - 1);
    int p = (idx >> 7) & (H_ - 1);
    int b = idx >> 14;
    size_t tid = ((size_t)b * W_ + q) * H_ + p;
    mct[tid] = m; dvt[tid] = d;
}

// -------------------------------------------------------------- K3: out_h (MFMA)
__global__ __launch_bounds__(256) void k_outh(
    const unsigned short* __restrict__ qkv_t,
    const float* __restrict__ mct, const float* __restrict__ dvt,
    unsigned short* __restrict__ oh_t)
{
    __shared__ __align__(16) unsigned short Pt[128 * 128];   // swizzled, 32 KB
    __shared__ __align__(16) unsigned char  Ubuf[18688];     // Ktp+Qp | Vl
    __shared__ float mloc[128], dloc[128];
    unsigned int* Ktp = (unsigned int*)Ubuf;                 // [128][20]
    unsigned int* Qp  = (unsigned int*)(Ubuf + 10240);       // [16][132]
    unsigned short* Vl = (unsigned short*)Ubuf;              // [64][128] swizzled

    const int t = threadIdx.x;
    const int beta = blockIdx.x;
    const int bb = blockIdx.y;
    const unsigned short* base = qkv_t + ((size_t)bb * W_ + beta) * OC_ * H_;

    if (t < 128) {
        size_t sidx = ((size_t)bb * W_ + beta) * H_ + t;
        mloc[t] = mct[sidx];
        dloc[t] = dvt[sidx];
    }
    stage_KQ(base, H_, Ktp, Qp, t);

    // T14: issue V(0) global loads now — latency hidden by P phase below
    const int vc  = t >> 4;           // 0..15 (row block)
    const int vi0 = (t & 15) * 8;     // col
    u8v vreg[4];
    {
        const unsigned short* vsrc = base + (size_t)64 * H_;
        #pragma unroll
        for (int q = 0; q < 4; ++q)
            vreg[q] = *(const u8v*)(vsrc + (size_t)(vc + q * 16) * H_ + vi0);
    }
    __syncthreads();

    const int lane = t & 63;
    const int wv = t >> 6;
    const int lg = lane >> 4;
    const int ll = lane & 15;
    const int jq0 = wv * 32;

    __builtin_amdgcn_s_setprio(1);
    #pragma unroll
    for (int mr = 0; mr < 8; ++mr) {
        const int i0 = mr * 16 + lg * 4;
        float mi[4], di[4];
        #pragma unroll
        for (int r = 0; r < 4; ++r) { mi[r] = mloc[i0 + r]; di[r] = dloc[i0 + r]; }
        #pragma unroll
        for (int nt = 0; nt < 2; ++nt) {
            int j = jq0 + nt * 16 + ll;
            f4v e = eqk_mfma(Ktp, Qp, mr, j, lg, ll);
            float p0 = (i0     == j) ? 0.f : __expf(e[0] - mi[0]) * di[0];
            float p1 = (i0 + 1 == j) ? 0.f : __expf(e[1] - mi[1]) * di[1];
            float p2 = (i0 + 2 == j) ? 0.f : __expf(e[2] - mi[2]) * di[2];
            float p3 = (i0 + 3 == j) ? 0.f : __expf(e[3] - mi[3]) * di[3];
            uint2 wd;
            wd.x = f2bf(p0) | ((unsigned int)f2bf(p1) << 16);
            wd.y = f2bf(p2) | ((unsigned int)f2bf(p3) << 16);
            int sidx = (j * 128 + i0) ^ ((j & 7) << 3);
            *(uint2*)&Pt[sidx] = wd;
        }
    }
    __builtin_amdgcn_s_setprio(0);

    unsigned short* outbase = oh_t + ((size_t)bb * W_ + beta) * C_ * H_;
    const int cw = (wv & 1) * 32;      // c base within chunk
    const int jw = (wv >> 1) * 64;     // j base

    for (int ch = 0; ch < 4; ++ch) {
        __syncthreads();   // Ktp/Qp (ch=0) or prev Vl reads done
        #pragma unroll
        for (int q = 0; q < 4; ++q) {
            int c = vc + q * 16;
            *(u8v*)&Vl[(c * 128 + vi0) ^ ((c & 7) << 3)] = vreg[q];
        }
        __syncthreads();
        if (ch < 3) {   // T14: next V chunk under this chunk's MFMA
            const unsigned short* vsrc = base + (size_t)(64 + (ch + 1) * 64) * H_;
            #pragma unroll
            for (int q = 0; q < 4; ++q)
                vreg[q] = *(const u8v*)(vsrc + (size_t)(vc + q * 16) * H_ + vi0);
        }

        f4v acc[2][4];
        #pragma unroll
        for (int cr = 0; cr < 2; ++cr)
            #pragma unroll
            for (int nt = 0; nt < 4; ++nt)
                acc[cr][nt] = (f4v){0.f, 0.f, 0.f, 0.f};

        __builtin_amdgcn_s_setprio(1);
        #pragma unroll
        for (int kk = 0; kk < 4; ++kk) {
            s8v afr[2];
            #pragma unroll
            for (int cr = 0; cr < 2; ++cr) {
                int crow = cw + cr * 16 + ll;
                afr[cr] = *(const s8v*)&Vl[(crow * 128 + kk * 32 + lg * 8) ^ ((crow & 7) << 3)];
            }
            #pragma unroll
            for (int nt = 0; nt < 4; ++nt) {
                int j = jw + nt * 16 + ll;
                s8v bfr = *(const s8v*)&Pt[(j * 128 + kk * 32 + lg * 8) ^ ((j & 7) << 3)];
                acc[0][nt] = __builtin_amdgcn_mfma_f32_16x16x32_bf16(afr[0], bfr, acc[0][nt], 0, 0, 0);
                acc[1][nt] = __builtin_amdgcn_mfma_f32_16x16x32_bf16(afr[1], bfr, acc[1][nt], 0, 0, 0);
            }
        }
        __builtin_amdgcn_s_setprio(0);
        #pragma unroll
        for (int cr = 0; cr < 2; ++cr)
            #pragma unroll
            for (int nt = 0; nt < 4; ++nt) {
                int j = jw + nt * 16 + ll;
                #pragma unroll
                for (int r = 0; r < 4; ++r) {
                    int c = ch * 64 + cw + cr * 16 + lg * 4 + r;
                    outbase[(size_t)c * H_ + j] = f2bf(acc[cr][nt][r]);
                }
            }
    }
}

// -------------------------------------------------------------- K4: out_w (MFMA)
__global__ __launch_bounds__(256) void k_outw(
    const unsigned short* __restrict__ qkv,
    const float* __restrict__ mc, const float* __restrict__ dv_,
    unsigned short* __restrict__ ow)
{
    __shared__ __align__(16) unsigned short Pt[128 * 128];
    __shared__ __align__(16) unsigned char  Ubuf[18688];
    __shared__ float mloc[128], dloc[128];
    unsigned int* Ktp = (unsigned int*)Ubuf;
    unsigned int* Qp  = (unsigned int*)(Ubuf + 10240);
    unsigned short* Vl = (unsigned short*)Ubuf;

    const int t = threadIdx.x;
    const int alpha = blockIdx.x;
    const int bb = blockIdx.y;
    const unsigned short* base = qkv + (size_t)bb * OC_ * HW_ + (size_t)alpha * W_;

    if (t < 128) {
        size_t sidx = ((size_t)bb * H_ + alpha) * W_ + t;
        mloc[t] = mc[sidx];
        dloc[t] = dv_[sidx];
    }
    stage_KQ(base, HW_, Ktp, Qp, t);

    const int vc  = t >> 4;
    const int vi0 = (t & 15) * 8;
    u8v vreg[4];
    {
        const unsigned short* vsrc = base + (size_t)64 * HW_;
        #pragma unroll
        for (int q = 0; q < 4; ++q)
            vreg[q] = *(const u8v*)(vsrc + (size_t)(vc + q * 16) * HW_ + vi0);
    }
    __syncthreads();

    const int lane = t & 63;
    const int wv = t >> 6;
    const int lg = lane >> 4;
    const int ll = lane & 15;
    const int jq0 = wv * 32;

    __builtin_amdgcn_s_setprio(1);
    #pragma unroll
    for (int mr = 0; mr < 8; ++mr) {
        const int i0 = mr * 16 + lg * 4;
        float mi[4], di[4];
        #pragma unroll
        for (int r = 0; r < 4; ++r) { mi[r] = mloc[i0 + r]; di[r] = dloc[i0 + r]; }
        #pragma unroll
        for (int nt = 0; nt < 2; ++nt) {
            int j = jq0 + nt * 16 + ll;
            f4v e = eqk_mfma(Ktp, Qp, mr, j, lg, ll);
            float p0 = __expf(e[0] - mi[0]) * di[0];      // no diag mask in e_w
            float p1 = __expf(e[1] - mi[1]) * di[1];
            float p2 = __expf(e[2] - mi[2]) * di[2];
            float p3 = __expf(e[3] - mi[3]) * di[3];
            uint2 wd;
            wd.x = f2bf(p0) | ((unsigned int)f2bf(p1) << 16);
            wd.y = f2bf(p2) | ((unsigned int)f2bf(p3) << 16);
            int sidx = (j * 128 + i0) ^ ((j & 7) << 3);
            *(uint2*)&Pt[sidx] = wd;
        }
    }
    __builtin_amdgcn_s_setprio(0);

    unsigned short* obase = ow + (size_t)bb * C_ * HW_ + (size_t)alpha * W_;
    const int cw = (wv & 1) * 32;
    const int jw = (wv >> 1) * 64;

    for (int ch = 0; ch < 4; ++ch) {
        __syncthreads();
        #pragma unroll
        for (int q = 0; q < 4; ++q) {
            int c = vc + q * 16;
            *(u8v*)&Vl[(c * 128 + vi0) ^ ((c & 7) << 3)] = vreg[q];
        }
        __syncthreads();
        if (ch < 3) {
            const unsigned short* vsrc = base + (size_t)(64 + (ch + 1) * 64) * HW_;
            #pragma unroll
            for (int q = 0; q < 4; ++q)
                vreg[q] = *(const u8v*)(vsrc + (size_t)(vc + q * 16) * HW_ + vi0);
        }

        f4v acc[2][4];
        #pragma unroll
        for (int cr = 0; cr < 2; ++cr)
            #pragma unroll
            for (int nt = 0; nt < 4; ++nt)
                acc[cr][nt] = (f4v){0.f, 0.f, 0.f, 0.f};

        __builtin_amdgcn_s_setprio(1);
        #pragma unroll
        for (int kk = 0; kk < 4; ++kk) {
            s8v afr[2];
            #pragma unroll
            for (int cr = 0; cr < 2; ++cr) {
                int crow = cw + cr * 16 + ll;
                afr[cr] = *(const s8v*)&Vl[(crow * 128 + kk * 32 + lg * 8) ^ ((crow & 7) << 3)];
            }
            #pragma unroll
            for (int nt = 0; nt < 4; ++nt) {
                int j = jw + nt * 16 + ll;
                s8v bfr = *(const s8v*)&Pt[(j * 128 + kk * 32 + lg * 8) ^ ((j & 7) << 3)];
                acc[0][nt] = __builtin_amdgcn_mfma_f32_16x16x32_bf16(afr[0], bfr, acc[0][nt], 0, 0, 0);
                acc[1][nt] = __builtin_amdgcn_mfma_f32_16x16x32_bf16(afr[1], bfr, acc[1][nt], 0, 0, 0);
            }
        }
        __builtin_amdgcn_s_setprio(0);
        #pragma unroll
        for (int cr = 0; cr < 2; ++cr)
            #pragma unroll
            for (int nt = 0; nt < 4; ++nt) {
                int j = jw + nt * 16 + ll;
                #pragma unroll
                for (int r = 0; r < 4; ++r) {
                    int c = ch * 64 + cw + cr * 16 + lg * 4 + r;
                    obase[(size_t)c * HW_ + j] = f2bf(acc[cr][nt][r]);
                }
            }
    }
}

// ------------------------------- K5 v3: out = x + gamma*(ow + oh^T)
// per-(c,b) plane; NON-TEMPORAL out stores (out never re-read -> keep L2/L3
// clean for x/oh/ow), NT loads for last-consumer streams.
__global__ __launch_bounds__(256) void k_combine(
    const unsigned short* __restrict__ oh_t, const unsigned short* __restrict__ ow,
    const float* __restrict__ x, const float* __restrict__ gamma_p,
    float* __restrict__ out, int b0)
{
    __shared__ unsigned short tile[128][130];   // [w][h], pitch 130 (bank-safe)
    const int t  = threadIdx.x;
    const int c  = blockIdx.x;
    const int bb = blockIdx.y;
    const float gamma = gamma_p[0];

    // load oh_t[bb][w][c][0..127]: 128 rows x 256 B contiguous
    {
        const unsigned short* src = oh_t + (size_t)bb * W_ * C_ * H_ + (size_t)c * H_;
        const int row = t >> 1;             // 0..127 (w)
        const int h0  = (t & 1) * 64;       // half-row
        #pragma unroll
        for (int q = 0; q < 8; ++q) {
            u8v v = __builtin_nontemporal_load(
                (const u8v*)(src + (size_t)row * (C_ * H_) + h0 + q * 8));
            *(u8v*)&tile[row][h0 + q * 8] = v;
        }
    }
    __syncthreads();

    const size_t pbase = ((size_t)bb * C_ + c) * HW_;
    const size_t gbase = ((size_t)(b0 + bb) * C_ + c) * HW_;
    const int w4 = (t & 31) * 4;
    const int hb = t >> 5;                  // 0..7
    #pragma unroll
    for (int hh = 0; hh < 16; ++hh) {
        int h = hb + hh * 8;                // block sweeps h in 8-row chunks
        size_t idx = (size_t)h * W_ + w4;
        f4v xv = __builtin_nontemporal_load((const f4v*)(x + gbase + idx));
        u4v o4 = __builtin_nontemporal_load((const u4v*)(ow + pbase + idx));
        f4v r;
        r[0] = xv[0] + gamma * (bfu(o4[0]) + bfu(tile[w4 + 0][h]));
        r[1] = xv[1] + gamma * (bfu(o4[1]) + bfu(tile[w4 + 1][h]));
        r[2] = xv[2] + gamma * (bfu(o4[2]) + bfu(tile[w4 + 2][h]));
        r[3] = xv[3] + gamma * (bfu(o4[3]) + bfu(tile[w4 + 3][h]));
        __builtin_nontemporal_store(r, (f4v*)(out + gbase + idx));
    }
}

// ------------------------------------------------------------------- launcher
extern "C" void kernel_launch(void* const* d_in, const int* in_sizes, int n_in,
                              void* d_out, int out_size, void* d_ws, size_t ws_size,
                              hipStream_t stream)
{
    (void)in_sizes; (void)n_in; (void)out_size;
    const float* x  = (const float*)d_in[0];
    const float* wq = (const float*)d_in[1];
    const float* bq = (const float*)d_in[2];
    const float* wk = (const float*)d_in[3];
    const float* bk = (const float*)d_in[4];
    const float* wv = (const float*)d_in[5];
    const float* bv = (const float*)d_in[6];
    const float* gm = (const float*)d_in[7];
    float* out = (float*)d_out;

    const size_t e_qkv  = (size_t)OC_ * HW_;   // bf16 elements
    const size_t e_out  = (size_t)C_ * HW_;    // bf16 elements
    const size_t e_stat = (size_t)HW_;         // fp32 elements
    const size_t perb_bytes = (e_qkv * 2 + e_out * 2) * 2 + e_stat * 8 * 4;
    const size_t wb_bytes = (size_t)OC_ * C_ * 2;
    int nbcap = (int)((ws_size - wb_bytes) / perb_bytes);
    if (nbcap > 8) nbcap = 8;
    if (nbcap < 1) nbcap = 1;

    unsigned short* Wb    = (unsigned short*)d_ws;
    unsigned short* qkv   = Wb    + (size_t)OC_ * C_;
    unsigned short* qkv_t = qkv   + e_qkv * nbcap;
    unsigned short* oh    = qkv_t + e_qkv * nbcap;
    unsigned short* ow    = oh    + e_out * nbcap;
    float* mh  = (float*)(ow + e_out * nbcap);
    float* sh  = mh  + e_stat * nbcap;
    float* mw  = sh  + e_stat * nbcap;
    float* sw  = mw  + e_stat * nbcap;
    float* mc  = sw  + e_stat * nbcap;
    float* dv  = mc  + e_stat * nbcap;
    float* mct = dv  + e_stat * nbcap;
    float* dvt = mct + e_stat * nbcap;

    k_wconv<<<dim3(80), 256, 0, stream>>>(wq, wk, wv, Wb);

    for (int b0 = 0; b0 < 8; b0 += nbcap) {
        int nb = 8 - b0 < nbcap ? 8 - b0 : nbcap;
        k_qkv<<<dim3(HW_ / 128, 5, nb), 256, 0, stream>>>(
            x, Wb, bq, bk, bv, qkv, b0);
        k_transpose_qkv<<<dim3(16, OC_, nb), dim3(32, 8), 0, stream>>>(qkv, qkv_t);
        k_stats<<<dim3(128, 2, nb), 256, 0, stream>>>(
            qkv_t, qkv, mh, sh, mw, sw);
        int nstat = nb * HW_;
        k_prep<<<dim3((nstat + 255) / 256), 256, 0, stream>>>(
            mh, sh, mw, sw, mc, dv, mct, dvt, nstat);
        k_outh<<<dim3(W_, nb), 256, 0, stream>>>(qkv_t, mct, dvt, oh);
        k_outw<<<dim3(H_, nb), 256, 0, stream>>>(qkv, mc, dv, ow);
        k_combine<<<dim3(C_, nb), 256, 0, stream>>>(
            oh, ow, x, gm, out, b0);
    }
}

// Round 17
// 283.133 us; speedup vs baseline: 1.0247x; 1.0247x over previous
//
#include <hip/hip_runtime.h>
#include <math.h>

#define C_   256
#define CQ_  32
#define H_   128
#define W_   128
#define HW_  (H_ * W_)
#define OC_  320   // 0..31 q, 32..63 k, 64..319 v

typedef __attribute__((ext_vector_type(8))) short  s8v;   // 8 bf16 (A/B frag)
typedef __attribute__((ext_vector_type(4))) float  f4v;   // 4 fp32 (C/D frag)
typedef __attribute__((ext_vector_type(8))) unsigned short u8v;
typedef __attribute__((ext_vector_type(4))) unsigned short u4v;

__device__ inline unsigned short f2bf(float f) {
    unsigned int u = __float_as_uint(f);
    unsigned int r = (u + 0x7fffu + ((u >> 16) & 1u)) >> 16;
    return (unsigned short)r;
}
__device__ inline float bfu(unsigned short u) {
    return __uint_as_float((unsigned int)u << 16);
}

// ------------------------------------------------ K0: W -> bf16 (320x256)
__global__ __launch_bounds__(256) void k_wconv(
    const float* __restrict__ wq, const float* __restrict__ wk,
    const float* __restrict__ wv, unsigned short* __restrict__ Wb)
{
    int idx4 = blockIdx.x * 256 + threadIdx.x;     // 20480 total
    int e = idx4 * 4;
    int oc = e >> 8, k = e & 255;
    const float* src;
    if (oc < 32)      src = wq + (size_t)oc * C_ + k;
    else if (oc < 64) src = wk + (size_t)(oc - 32) * C_ + k;
    else              src = wv + (size_t)(oc - 64) * C_ + k;
    float4 v = *(const float4*)src;
    u4v o;
    o[0] = f2bf(v.x); o[1] = f2bf(v.y); o[2] = f2bf(v.z); o[3] = f2bf(v.w);
    *(u4v*)(Wb + e) = o;
}

// ---------------------------------------------------------- K1: QKV MFMA GEMM
// R10 v5 (proven 90 µs) + T5 setprio around MFMA cluster.
__global__ __launch_bounds__(256) void k_qkv(
    const float* __restrict__ x, const unsigned short* __restrict__ Wb,
    const float* __restrict__ bq, const float* __restrict__ bk,
    const float* __restrict__ bv,
    unsigned short* __restrict__ qkv, int b0)
{
    __shared__ __align__(16) unsigned short Wl[2][64][72];   // 18.4 KB
    __shared__ __align__(16) unsigned int   Xp[2][32 * 132]; // 33.8 KB
    const int t = threadIdx.x;
    const int lane = t & 63;
    const int wave = t >> 6;
    const int n0 = blockIdx.x * 128;
    const int ocblk = blockIdx.y * 64;
    const int bb = blockIdx.z;
    const float* xb = x + (size_t)(b0 + bb) * C_ * HW_;

    const int lg = lane >> 4;      // 0..3
    const int ll = lane & 15;      // 0..15
    const int n_w = wave * 32;

    const int kp8 = t >> 5;          // 0..7
    const int n4  = (t & 31) * 4;    // 0..124
    const int wrow = t >> 3;         // 0..31
    const int wcg  = (t & 7) * 8;    // 0..56 (shorts)
    float4 ra[4], rb[4];
    u8v wreg[2];

    // ---- prologue: chunk 0 -> regs -> buf0; issue chunk 1 loads
    #pragma unroll
    for (int p = 0; p < 4; ++p) {
        int krow = (p * 8 + kp8) * 2;
        ra[p] = *(const float4*)(xb + (size_t)krow * HW_ + n0 + n4);
        rb[p] = *(const float4*)(xb + (size_t)(krow + 1) * HW_ + n0 + n4);
    }
    #pragma unroll
    for (int q = 0; q < 2; ++q)
        wreg[q] = *(const u8v*)(Wb + (size_t)(ocblk + wrow + q * 32) * C_ + wcg);

    #pragma unroll
    for (int p = 0; p < 4; ++p) {
        uint4 d;
        const float* af  = (const float*)&ra[p];
        const float* bf_ = (const float*)&rb[p];
        #pragma unroll
        for (int i = 0; i < 4; ++i) {
            unsigned int lo = (__float_as_uint(af[i])  + 0x8000u) >> 16;
            unsigned int hi = (__float_as_uint(bf_[i]) + 0x8000u) & 0xffff0000u;
            ((unsigned int*)&d)[i] = hi | lo;
        }
        *(uint4*)&Xp[0][(p * 8 + kp8) * 132 + n4] = d;
    }
    #pragma unroll
    for (int q = 0; q < 2; ++q)
        *(u8v*)&Wl[0][wrow + q * 32][wcg] = wreg[q];

    #pragma unroll
    for (int p = 0; p < 4; ++p) {
        int krow = 64 + (p * 8 + kp8) * 2;
        ra[p] = *(const float4*)(xb + (size_t)krow * HW_ + n0 + n4);
        rb[p] = *(const float4*)(xb + (size_t)(krow + 1) * HW_ + n0 + n4);
    }
    #pragma unroll
    for (int q = 0; q < 2; ++q)
        wreg[q] = *(const u8v*)(Wb + (size_t)(ocblk + wrow + q * 32) * C_ + 64 + wcg);

    f4v acc[4][2];
    #pragma unroll
    for (int mr = 0; mr < 4; ++mr)
        #pragma unroll
        for (int nr = 0; nr < 2; ++nr)
            acc[mr][nr] = (f4v){0.f, 0.f, 0.f, 0.f};

    __syncthreads();   // buf0 ready

    #pragma unroll
    for (int kc = 0; kc < 4; ++kc) {
        const int cur = kc & 1;
        if (kc < 3) {
            #pragma unroll
            for (int p = 0; p < 4; ++p) {
                uint4 d;
                const float* af  = (const float*)&ra[p];
                const float* bf_ = (const float*)&rb[p];
                #pragma unroll
                for (int i = 0; i < 4; ++i) {
                    unsigned int lo = (__float_as_uint(af[i])  + 0x8000u) >> 16;
                    unsigned int hi = (__float_as_uint(bf_[i]) + 0x8000u) & 0xffff0000u;
                    ((unsigned int*)&d)[i] = hi | lo;
                }
                *(uint4*)&Xp[cur ^ 1][(p * 8 + kp8) * 132 + n4] = d;
            }
            #pragma unroll
            for (int q = 0; q < 2; ++q)
                *(u8v*)&Wl[cur ^ 1][wrow + q * 32][wcg] = wreg[q];
        }
        if (kc < 2) {
            #pragma unroll
            for (int p = 0; p < 4; ++p) {
                int krow = (kc + 2) * 64 + (p * 8 + kp8) * 2;
                ra[p] = *(const float4*)(xb + (size_t)krow * HW_ + n0 + n4);
                rb[p] = *(const float4*)(xb + (size_t)(krow + 1) * HW_ + n0 + n4);
            }
            #pragma unroll
            for (int q = 0; q < 2; ++q)
                wreg[q] = *(const u8v*)(
                    Wb + (size_t)(ocblk + wrow + q * 32) * C_ + (kc + 2) * 64 + wcg);
        }
        __builtin_amdgcn_s_setprio(1);
        #pragma unroll
        for (int ks = 0; ks < 2; ++ks) {
            s8v afr[4];
            #pragma unroll
            for (int mr = 0; mr < 4; ++mr)
                afr[mr] = *(const s8v*)&Wl[cur][mr * 16 + ll][ks * 32 + lg * 8];
            #pragma unroll
            for (int nr = 0; nr < 2; ++nr) {
                int4 bd;
                #pragma unroll
                for (int e2 = 0; e2 < 4; ++e2)
                    ((int*)&bd)[e2] =
                        Xp[cur][(ks * 16 + lg * 4 + e2) * 132 + n_w + nr * 16 + ll];
                s8v bfr = *(s8v*)&bd;
                #pragma unroll
                for (int mr = 0; mr < 4; ++mr)
                    acc[mr][nr] = __builtin_amdgcn_mfma_f32_16x16x32_bf16(
                        afr[mr], bfr, acc[mr][nr], 0, 0, 0);
            }
        }
        __builtin_amdgcn_s_setprio(0);
        __syncthreads();   // buf[cur^1] writes visible; buf[cur] reads done
    }

    #pragma unroll
    for (int mr = 0; mr < 4; ++mr) {
        float bias[4];
        #pragma unroll
        for (int r = 0; r < 4; ++r) {
            int oc = ocblk + mr * 16 + lg * 4 + r;
            if (oc < 32)      bias[r] = bq[oc];
            else if (oc < 64) bias[r] = bk[oc - 32];
            else              bias[r] = bv[oc - 64];
        }
        #pragma unroll
        for (int nr = 0; nr < 2; ++nr) {
            int n = n0 + n_w + nr * 16 + ll;
            #pragma unroll
            for (int r = 0; r < 4; ++r) {
                int oc = ocblk + mr * 16 + lg * 4 + r;
                qkv[((size_t)bb * OC_ + oc) * HW_ + n] = f2bf(acc[mr][nr][r] + bias[r]);
            }
        }
    }
}

// ------------------------------------------------- K1b: transpose to (b,w,oc,h)
__global__ __launch_bounds__(256) void k_transpose_qkv(
    const unsigned short* __restrict__ qkv, unsigned short* __restrict__ qkv_t)
{
    __shared__ unsigned short tile[32][34];
    const int bb = blockIdx.z;
    const int oc = blockIdx.y;
    const int th = (blockIdx.x & 3) * 32;
    const int tw = (blockIdx.x >> 2) * 32;
    const unsigned short* src = qkv + ((size_t)bb * OC_ + oc) * HW_;
    #pragma unroll
    for (int r = 0; r < 4; ++r) {
        int h = threadIdx.y * 4 + r;
        tile[h][threadIdx.x] = src[(size_t)(th + h) * W_ + tw + threadIdx.x];
    }
    __syncthreads();
    unsigned short* dst = qkv_t + (size_t)bb * W_ * OC_ * H_;
    #pragma unroll
    for (int r = 0; r < 4; ++r) {
        int wl = threadIdx.y * 4 + r;
        dst[((size_t)(tw + wl) * OC_ + oc) * H_ + th + threadIdx.x] = tile[threadIdx.x][wl];
    }
}

// ---------------------------------------------------------------- shared helpers
__device__ inline void stage_KQ(const unsigned short* base, int cstride,
                                unsigned int* Ktp, unsigned int* Qp, int t)
{
    {   // Ktp: 128 rows x 2 halves = 256 units
        int i = t & 127, half = t >> 7, c0 = half * 16;
        unsigned int kr[16];
        #pragma unroll
        for (int cc = 0; cc < 16; ++cc)
            kr[cc] = base[(size_t)(32 + c0 + cc) * cstride + i];
        uint4 d0, d1;
        #pragma unroll
        for (int e2 = 0; e2 < 4; ++e2)
            ((unsigned int*)&d0)[e2] = kr[2 * e2] | (kr[2 * e2 + 1] << 16);
        #pragma unroll
        for (int e2 = 0; e2 < 4; ++e2)
            ((unsigned int*)&d1)[e2] = kr[8 + 2 * e2] | (kr[9 + 2 * e2] << 16);
        *(uint4*)&Ktp[i * 20 + half * 8]     = d0;
        *(uint4*)&Ktp[i * 20 + half * 8 + 4] = d1;
    }
    {   // Qp: 16 c2 x 16 j-groups = 256 units
        int c2 = t >> 4, j8 = (t & 15) * 8;
        u8v qa = *(const u8v*)(base + (size_t)(2 * c2) * cstride + j8);
        u8v qb = *(const u8v*)(base + (size_t)(2 * c2 + 1) * cstride + j8);
        uint4 e0, e1;
        #pragma unroll
        for (int e = 0; e < 4; ++e)
            ((unsigned int*)&e0)[e] =
                (unsigned int)qa[e] | ((unsigned int)qb[e] << 16);
        #pragma unroll
        for (int e = 0; e < 4; ++e)
            ((unsigned int*)&e1)[e] =
                (unsigned int)qa[4 + e] | ((unsigned int)qb[4 + e] << 16);
        *(uint4*)&Qp[c2 * 132 + j8]     = e0;
        *(uint4*)&Qp[c2 * 132 + j8 + 4] = e1;
    }
}

__device__ inline f4v eqk_mfma(const unsigned int* Ktp, const unsigned int* Qp,
                               int mr, int j, int lg, int ll)
{
    s8v afr = *(const s8v*)&Ktp[(mr * 16 + ll) * 20 + lg * 4];
    int4 bd;
    #pragma unroll
    for (int e2 = 0; e2 < 4; ++e2)
        ((int*)&bd)[e2] = Qp[(lg * 4 + e2) * 132 + j];
    s8v bfr = *(s8v*)&bd;
    return __builtin_amdgcn_mfma_f32_16x16x32_bf16(
        afr, bfr, (f4v){0.f, 0.f, 0.f, 0.f}, 0, 0, 0);
}

// ----------------------- K2: stats, both axes (mode = blockIdx.y; 0=h, 1=w)
__global__ __launch_bounds__(256) void k_stats(
    const unsigned short* __restrict__ qkv_t, const unsigned short* __restrict__ qkv,
    float* __restrict__ mh, float* __restrict__ sh,
    float* __restrict__ mw, float* __restrict__ sw)
{
    __shared__ __align__(16) unsigned int Ktp[128 * 20];
    __shared__ __align__(16) unsigned int Qp[16 * 132];
    const int t = threadIdx.x;
    const int pos = blockIdx.x;          // beta (mode 0) or alpha (mode 1)
    const int mode = blockIdx.y;
    const int bb = blockIdx.z;
    const unsigned short* base;
    int cstride;
    if (mode == 0) {
        base = qkv_t + ((size_t)bb * W_ + pos) * OC_ * H_;
        cstride = H_;
    } else {
        base = qkv + (size_t)bb * OC_ * HW_ + (size_t)pos * W_;
        cstride = HW_;
    }
    stage_KQ(base, cstride, Ktp, Qp, t);
    __syncthreads();

    const int lane = t & 63;
    const int wv = t >> 6;
    const int lg = lane >> 4;
    const int ll = lane & 15;

    #pragma unroll
    for (int ml = 0; ml < 2; ++ml) {
        const int mr = wv * 2 + ml;
        const int i0 = mr * 16 + lg * 4;
        f4v ef[8];
        #pragma unroll
        for (int nt = 0; nt < 8; ++nt) {
            f4v e = eqk_mfma(Ktp, Qp, mr, nt * 16 + ll, lg, ll);
            if (mode == 0) {
                int j = nt * 16 + ll;
                #pragma unroll
                for (int r = 0; r < 4; ++r)
                    if (i0 + r == j) e[r] = -INFINITY;   // diag mask (e_h only)
            }
            ef[nt] = e;
        }
        #pragma unroll
        for (int r = 0; r < 4; ++r) {
            float mm = -INFINITY;
            #pragma unroll
            for (int nt = 0; nt < 8; ++nt) mm = fmaxf(mm, ef[nt][r]);
            #pragma unroll
            for (int s = 1; s < 16; s <<= 1) mm = fmaxf(mm, __shfl_xor(mm, s));
            float ss = 0.f;
            #pragma unroll
            for (int nt = 0; nt < 8; ++nt) ss += __expf(ef[nt][r] - mm);
            #pragma unroll
            for (int s = 1; s < 16; s <<= 1) ss += __shfl_xor(ss, s);
            if (ll == 0) {
                int i = i0 + r;
                if (mode == 0) {
                    mh[((size_t)bb * H_ + i) * W_ + pos] = mm;
                    sh[((size_t)bb * H_ + i) * W_ + pos] = ss;
                } else {
                    mw[((size_t)bb * H_ + pos) * W_ + i] = mm;
                    sw[((size_t)bb * H_ + pos) * W_ + i] = ss;
                }
            }
        }
    }
}

// ------------------------------- K2c: combine stats -> m_comb, d_inv (+transposed)
__global__ __launch_bounds__(256) void k_prep(
    const float* __restrict__ mh, const float* __restrict__ sh,
    const float* __restrict__ mw, const float* __restrict__ sw,
    float* __restrict__ mc, float* __restrict__ dv,
    float* __restrict__ mct, float* __restrict__ dvt, int n)
{
    int idx = blockIdx.x * 256 + threadIdx.x;
    if (idx >= n) return;
    float m1 = mh[idx], s1 = sh[idx], m2 = mw[idx], s2 = sw[idx];
    float m = fmaxf(m1, m2);
    float d = 1.f / (s1 * __expf(m1 - m) + s2 * __expf(m2 - m));
    mc[idx] = m; dv[idx] = d;
    int q = idx & (W_ - 1);
    int p = (idx >> 7) & (H_ - 1);
    int b = idx >> 14;
    size_t tid = ((size_t)b * W_ + q) * H_ + p;
    mct[tid] = m; dvt[tid] = d;
}

// -------------------------------------------------------------- K3: out_h (MFMA)
__global__ __launch_bounds__(256) void k_outh(
    const unsigned short* __restrict__ qkv_t,
    const float* __restrict__ mct, const float* __restrict__ dvt,
    unsigned short* __restrict__ oh_t)
{
    __shared__ __align__(16) unsigned short Pt[128 * 128];   // swizzled, 32 KB
    __shared__ __align__(16) unsigned char  Ubuf[18688];     // Ktp+Qp | Vl
    __shared__ float mloc[128], dloc[128];
    unsigned int* Ktp = (unsigned int*)Ubuf;                 // [128][20]
    unsigned int* Qp  = (unsigned int*)(Ubuf + 10240);       // [16][132]
    unsigned short* Vl = (unsigned short*)Ubuf;              // [64][128] swizzled

    const int t = threadIdx.x;
    const int beta = blockIdx.x;
    const int bb = blockIdx.y;
    const unsigned short* base = qkv_t + ((size_t)bb * W_ + beta) * OC_ * H_;

    if (t < 128) {
        size_t sidx = ((size_t)bb * W_ + beta) * H_ + t;
        mloc[t] = mct[sidx];
        dloc[t] = dvt[sidx];
    }
    stage_KQ(base, H_, Ktp, Qp, t);

    // T14: issue V(0) global loads now — latency hidden by P phase below
    const int vc  = t >> 4;           // 0..15 (row block)
    const int vi0 = (t & 15) * 8;     // col
    u8v vreg[4];
    {
        const unsigned short* vsrc = base + (size_t)64 * H_;
        #pragma unroll
        for (int q = 0; q < 4; ++q)
            vreg[q] = *(const u8v*)(vsrc + (size_t)(vc + q * 16) * H_ + vi0);
    }
    __syncthreads();

    const int lane = t & 63;
    const int wv = t >> 6;
    const int lg = lane >> 4;
    const int ll = lane & 15;
    const int jq0 = wv * 32;

    __builtin_amdgcn_s_setprio(1);
    #pragma unroll
    for (int mr = 0; mr < 8; ++mr) {
        const int i0 = mr * 16 + lg * 4;
        float mi[4], di[4];
        #pragma unroll
        for (int r = 0; r < 4; ++r) { mi[r] = mloc[i0 + r]; di[r] = dloc[i0 + r]; }
        #pragma unroll
        for (int nt = 0; nt < 2; ++nt) {
            int j = jq0 + nt * 16 + ll;
            f4v e = eqk_mfma(Ktp, Qp, mr, j, lg, ll);
            float p0 = (i0     == j) ? 0.f : __expf(e[0] - mi[0]) * di[0];
            float p1 = (i0 + 1 == j) ? 0.f : __expf(e[1] - mi[1]) * di[1];
            float p2 = (i0 + 2 == j) ? 0.f : __expf(e[2] - mi[2]) * di[2];
            float p3 = (i0 + 3 == j) ? 0.f : __expf(e[3] - mi[3]) * di[3];
            uint2 wd;
            wd.x = f2bf(p0) | ((unsigned int)f2bf(p1) << 16);
            wd.y = f2bf(p2) | ((unsigned int)f2bf(p3) << 16);
            int sidx = (j * 128 + i0) ^ ((j & 7) << 3);
            *(uint2*)&Pt[sidx] = wd;
        }
    }
    __builtin_amdgcn_s_setprio(0);

    unsigned short* outbase = oh_t + ((size_t)bb * W_ + beta) * C_ * H_;
    const int cw = (wv & 1) * 32;      // c base within chunk
    const int jw = (wv >> 1) * 64;     // j base

    for (int ch = 0; ch < 4; ++ch) {
        __syncthreads();   // Ktp/Qp (ch=0) or prev Vl reads done
        #pragma unroll
        for (int q = 0; q < 4; ++q) {
            int c = vc + q * 16;
            *(u8v*)&Vl[(c * 128 + vi0) ^ ((c & 7) << 3)] = vreg[q];
        }
        __syncthreads();
        if (ch < 3) {   // T14: next V chunk under this chunk's MFMA
            const unsigned short* vsrc = base + (size_t)(64 + (ch + 1) * 64) * H_;
            #pragma unroll
            for (int q = 0; q < 4; ++q)
                vreg[q] = *(const u8v*)(vsrc + (size_t)(vc + q * 16) * H_ + vi0);
        }

        f4v acc[2][4];
        #pragma unroll
        for (int cr = 0; cr < 2; ++cr)
            #pragma unroll
            for (int nt = 0; nt < 4; ++nt)
                acc[cr][nt] = (f4v){0.f, 0.f, 0.f, 0.f};

        __builtin_amdgcn_s_setprio(1);
        #pragma unroll
        for (int kk = 0; kk < 4; ++kk) {
            s8v afr[2];
            #pragma unroll
            for (int cr = 0; cr < 2; ++cr) {
                int crow = cw + cr * 16 + ll;
                afr[cr] = *(const s8v*)&Vl[(crow * 128 + kk * 32 + lg * 8) ^ ((crow & 7) << 3)];
            }
            #pragma unroll
            for (int nt = 0; nt < 4; ++nt) {
                int j = jw + nt * 16 + ll;
                s8v bfr = *(const s8v*)&Pt[(j * 128 + kk * 32 + lg * 8) ^ ((j & 7) << 3)];
                acc[0][nt] = __builtin_amdgcn_mfma_f32_16x16x32_bf16(afr[0], bfr, acc[0][nt], 0, 0, 0);
                acc[1][nt] = __builtin_amdgcn_mfma_f32_16x16x32_bf16(afr[1], bfr, acc[1][nt], 0, 0, 0);
            }
        }
        __builtin_amdgcn_s_setprio(0);
        #pragma unroll
        for (int cr = 0; cr < 2; ++cr)
            #pragma unroll
            for (int nt = 0; nt < 4; ++nt) {
                int j = jw + nt * 16 + ll;
                #pragma unroll
                for (int r = 0; r < 4; ++r) {
                    int c = ch * 64 + cw + cr * 16 + lg * 4 + r;
                    outbase[(size_t)c * H_ + j] = f2bf(acc[cr][nt][r]);
                }
            }
    }
}

// -------------------------------------------------------------- K4: out_w (MFMA)
__global__ __launch_bounds__(256) void k_outw(
    const unsigned short* __restrict__ qkv,
    const float* __restrict__ mc, const float* __restrict__ dv_,
    unsigned short* __restrict__ ow)
{
    __shared__ __align__(16) unsigned short Pt[128 * 128];
    __shared__ __align__(16) unsigned char  Ubuf[18688];
    __shared__ float mloc[128], dloc[128];
    unsigned int* Ktp = (unsigned int*)Ubuf;
    unsigned int* Qp  = (unsigned int*)(Ubuf + 10240);
    unsigned short* Vl = (unsigned short*)Ubuf;

    const int t = threadIdx.x;
    const int alpha = blockIdx.x;
    const int bb = blockIdx.y;
    const unsigned short* base = qkv + (size_t)bb * OC_ * HW_ + (size_t)alpha * W_;

    if (t < 128) {
        size_t sidx = ((size_t)bb * H_ + alpha) * W_ + t;
        mloc[t] = mc[sidx];
        dloc[t] = dv_[sidx];
    }
    stage_KQ(base, HW_, Ktp, Qp, t);

    const int vc  = t >> 4;
    const int vi0 = (t & 15) * 8;
    u8v vreg[4];
    {
        const unsigned short* vsrc = base + (size_t)64 * HW_;
        #pragma unroll
        for (int q = 0; q < 4; ++q)
            vreg[q] = *(const u8v*)(vsrc + (size_t)(vc + q * 16) * HW_ + vi0);
    }
    __syncthreads();

    const int lane = t & 63;
    const int wv = t >> 6;
    const int lg = lane >> 4;
    const int ll = lane & 15;
    const int jq0 = wv * 32;

    __builtin_amdgcn_s_setprio(1);
    #pragma unroll
    for (int mr = 0; mr < 8; ++mr) {
        const int i0 = mr * 16 + lg * 4;
        float mi[4], di[4];
        #pragma unroll
        for (int r = 0; r < 4; ++r) { mi[r] = mloc[i0 + r]; di[r] = dloc[i0 + r]; }
        #pragma unroll
        for (int nt = 0; nt < 2; ++nt) {
            int j = jq0 + nt * 16 + ll;
            f4v e = eqk_mfma(Ktp, Qp, mr, j, lg, ll);
            float p0 = __expf(e[0] - mi[0]) * di[0];      // no diag mask in e_w
            float p1 = __expf(e[1] - mi[1]) * di[1];
            float p2 = __expf(e[2] - mi[2]) * di[2];
            float p3 = __expf(e[3] - mi[3]) * di[3];
            uint2 wd;
            wd.x = f2bf(p0) | ((unsigned int)f2bf(p1) << 16);
            wd.y = f2bf(p2) | ((unsigned int)f2bf(p3) << 16);
            int sidx = (j * 128 + i0) ^ ((j & 7) << 3);
            *(uint2*)&Pt[sidx] = wd;
        }
    }
    __builtin_amdgcn_s_setprio(0);

    unsigned short* obase = ow + (size_t)bb * C_ * HW_ + (size_t)alpha * W_;
    const int cw = (wv & 1) * 32;
    const int jw = (wv >> 1) * 64;

    for (int ch = 0; ch < 4; ++ch) {
        __syncthreads();
        #pragma unroll
        for (int q = 0; q < 4; ++q) {
            int c = vc + q * 16;
            *(u8v*)&Vl[(c * 128 + vi0) ^ ((c & 7) << 3)] = vreg[q];
        }
        __syncthreads();
        if (ch < 3) {
            const unsigned short* vsrc = base + (size_t)(64 + (ch + 1) * 64) * HW_;
            #pragma unroll
            for (int q = 0; q < 4; ++q)
                vreg[q] = *(const u8v*)(vsrc + (size_t)(vc + q * 16) * HW_ + vi0);
        }

        f4v acc[2][4];
        #pragma unroll
        for (int cr = 0; cr < 2; ++cr)
            #pragma unroll
            for (int nt = 0; nt < 4; ++nt)
                acc[cr][nt] = (f4v){0.f, 0.f, 0.f, 0.f};

        __builtin_amdgcn_s_setprio(1);
        #pragma unroll
        for (int kk = 0; kk < 4; ++kk) {
            s8v afr[2];
            #pragma unroll
            for (int cr = 0; cr < 2; ++cr) {
                int crow = cw + cr * 16 + ll;
                afr[cr] = *(const s8v*)&Vl[(crow * 128 + kk * 32 + lg * 8) ^ ((crow & 7) << 3)];
            }
            #pragma unroll
            for (int nt = 0; nt < 4; ++nt) {
                int j = jw + nt * 16 + ll;
                s8v bfr = *(const s8v*)&Pt[(j * 128 + kk * 32 + lg * 8) ^ ((j & 7) << 3)];
                acc[0][nt] = __builtin_amdgcn_mfma_f32_16x16x32_bf16(afr[0], bfr, acc[0][nt], 0, 0, 0);
                acc[1][nt] = __builtin_amdgcn_mfma_f32_16x16x32_bf16(afr[1], bfr, acc[1][nt], 0, 0, 0);
            }
        }
        __builtin_amdgcn_s_setprio(0);
        #pragma unroll
        for (int cr = 0; cr < 2; ++cr)
            #pragma unroll
            for (int nt = 0; nt < 4; ++nt) {
                int j = jw + nt * 16 + ll;
                #pragma unroll
                for (int r = 0; r < 4; ++r) {
                    int c = ch * 64 + cw + cr * 16 + lg * 4 + r;
                    obase[(size_t)c * HW_ + j] = f2bf(acc[cr][nt][r]);
                }
            }
    }
}

// ------------------------------- K5 v4: out = x + gamma*(ow + oh^T)
// per (c, b, h-half): plane layout (256B-contiguous oh_t rows), NO NT hints
// (R16 post-mortem: NT bypass starved a latency-bound kernel), half-plane
// tiles halve LDS (17 KB) -> ~2x blocks/CU for latency hiding.
__global__ __launch_bounds__(256) void k_combine(
    const unsigned short* __restrict__ oh_t, const unsigned short* __restrict__ ow,
    const float* __restrict__ x, const float* __restrict__ gamma_p,
    float* __restrict__ out, int b0)
{
    __shared__ unsigned short tile[128][66];    // [w][h-half], 16.9 KB
    const int t  = threadIdx.x;
    const int c  = blockIdx.x;
    const int hh0 = blockIdx.y * 64;            // h-half base
    const int bb = blockIdx.z;
    const float gamma = gamma_p[0];

    // load oh_t[bb][w][c][hh0..hh0+63]: 128 rows x 128 B contiguous
    {
        const unsigned short* src =
            oh_t + (size_t)bb * W_ * C_ * H_ + (size_t)c * H_ + hh0;
        const int row = t >> 1;                 // 0..127 (w)
        const int h0  = (t & 1) * 32;           // half of the 64-wide row
        #pragma unroll
        for (int q = 0; q < 4; ++q) {
            u8v v = *(const u8v*)(src + (size_t)row * (C_ * H_) + h0 + q * 8);
            *(u8v*)&tile[row][h0 + q * 8] = v;
        }
    }
    __syncthreads();

    const size_t pbase = ((size_t)bb * C_ + c) * HW_;
    const size_t gbase = ((size_t)(b0 + bb) * C_ + c) * HW_;
    const int w4 = (t & 31) * 4;
    const int hb = t >> 5;                      // 0..7
    #pragma unroll
    for (int hh = 0; hh < 8; ++hh) {
        int h = hh0 + hb + hh * 8;
        size_t idx = (size_t)h * W_ + w4;
        float4 xv = *(const float4*)(x + gbase + idx);
        u4v o4 = *(const u4v*)(ow + pbase + idx);
        float4 r;
        r.x = xv.x + gamma * (bfu(o4[0]) + bfu(tile[w4 + 0][h - hh0]));
        r.y = xv.y + gamma * (bfu(o4[1]) + bfu(tile[w4 + 1][h - hh0]));
        r.z = xv.z + gamma * (bfu(o4[2]) + bfu(tile[w4 + 2][h - hh0]));
        r.w = xv.w + gamma * (bfu(o4[3]) + bfu(tile[w4 + 3][h - hh0]));
        *(float4*)(out + gbase + idx) = r;
    }
}

// ------------------------------------------------------------------- launcher
extern "C" void kernel_launch(void* const* d_in, const int* in_sizes, int n_in,
                              void* d_out, int out_size, void* d_ws, size_t ws_size,
                              hipStream_t stream)
{
    (void)in_sizes; (void)n_in; (void)out_size;
    const float* x  = (const float*)d_in[0];
    const float* wq = (const float*)d_in[1];
    const float* bq = (const float*)d_in[2];
    const float* wk = (const float*)d_in[3];
    const float* bk = (const float*)d_in[4];
    const float* wv = (const float*)d_in[5];
    const float* bv = (const float*)d_in[6];
    const float* gm = (const float*)d_in[7];
    float* out = (float*)d_out;

    const size_t e_qkv  = (size_t)OC_ * HW_;   // bf16 elements
    const size_t e_out  = (size_t)C_ * HW_;    // bf16 elements
    const size_t e_stat = (size_t)HW_;         // fp32 elements
    const size_t perb_bytes = (e_qkv * 2 + e_out * 2) * 2 + e_stat * 8 * 4;
    const size_t wb_bytes = (size_t)OC_ * C_ * 2;
    int nbcap = (int)((ws_size - wb_bytes) / perb_bytes);
    if (nbcap > 8) nbcap = 8;
    if (nbcap < 1) nbcap = 1;

    unsigned short* Wb    = (unsigned short*)d_ws;
    unsigned short* qkv   = Wb    + (size_t)OC_ * C_;
    unsigned short* qkv_t = qkv   + e_qkv * nbcap;
    unsigned short* oh    = qkv_t + e_qkv * nbcap;
    unsigned short* ow    = oh    + e_out * nbcap;
    float* mh  = (float*)(ow + e_out * nbcap);
    float* sh  = mh  + e_stat * nbcap;
    float* mw  = sh  + e_stat * nbcap;
    float* sw  = mw  + e_stat * nbcap;
    float* mc  = sw  + e_stat * nbcap;
    float* dv  = mc  + e_stat * nbcap;
    float* mct = dv  + e_stat * nbcap;
    float* dvt = mct + e_stat * nbcap;

    k_wconv<<<dim3(80), 256, 0, stream>>>(wq, wk, wv, Wb);

    for (int b0 = 0; b0 < 8; b0 += nbcap) {
        int nb = 8 - b0 < nbcap ? 8 - b0 : nbcap;
        k_qkv<<<dim3(HW_ / 128, 5, nb), 256, 0, stream>>>(
            x, Wb, bq, bk, bv, qkv, b0);
        k_transpose_qkv<<<dim3(16, OC_, nb), dim3(32, 8), 0, stream>>>(qkv, qkv_t);
        k_stats<<<dim3(128, 2, nb), 256, 0, stream>>>(
            qkv_t, qkv, mh, sh, mw, sw);
        int nstat = nb * HW_;
        k_prep<<<dim3((nstat + 255) / 256), 256, 0, stream>>>(
            mh, sh, mw, sw, mc, dv, mct, dvt, nstat);
        k_outh<<<dim3(W_, nb), 256, 0, stream>>>(qkv_t, mct, dvt, oh);
        k_outw<<<dim3(H_, nb), 256, 0, stream>>>(qkv, mc, dv, ow);
        k_combine<<<dim3(C_, 2, nb), 256, 0, stream>>>(
            oh, ow, x, gm, out, b0);
    }
}